// Round 12
// baseline (298.487 us; speedup 1.0000x reference)
//
#include <hip/hip_runtime.h>
#include <math.h>

#define B_   2
#define S_   2048
#define D_   2048
#define H_   16
#define KVH_ 4
#define HD_  128
#define REP_ 4

typedef __attribute__((ext_vector_type(8))) short bf16x8;
typedef __attribute__((ext_vector_type(4))) short bf16x4;
typedef __attribute__((ext_vector_type(4))) float f32x4;

// 1/sqrt(128) * log2(e): folded into Q so flash scores are base-2 pre-scaled
#define QSCALE_LOG2E 0.1275266977097153f

__device__ __forceinline__ unsigned short f2bf(float x) {
    union { float f; unsigned u; } v; v.f = x;
    unsigned r = v.u + 0x7FFF + ((v.u >> 16) & 1);   // RNE
    return (unsigned short)(r >> 16);
}

// cheap round-half-up bf16 (used only for P; bias cancels in p/sum(p))
__device__ __forceinline__ unsigned short f2bf_fast(float x) {
    union { float f; unsigned u; } v; v.f = x;
    return (unsigned short)((v.u + 0x8000) >> 16);
}

// async global->LDS, 16B per lane; LDS dest is wave-uniform base + lane*16
__device__ __forceinline__ void gl_lds16(const unsigned short* g, unsigned short* l) {
    __builtin_amdgcn_global_load_lds(
        (const __attribute__((address_space(1))) unsigned int*)g,
        (__attribute__((address_space(3))) unsigned int*)l,
        16, 0, 0);
}

#define PH_BAR() do { asm volatile("" ::: "memory"); \
                      __builtin_amdgcn_s_barrier();  \
                      asm volatile("" ::: "memory"); } while (0)
#define VMW6 asm volatile("s_waitcnt vmcnt(6)" ::: "memory")
#define VMW4 asm volatile("s_waitcnt vmcnt(4)" ::: "memory")
#define VMW0 asm volatile("s_waitcnt vmcnt(0)" ::: "memory")

// ---------------------------------------------------------------------------
// cast fp32 -> bf16 (elementwise)
// ---------------------------------------------------------------------------
__global__ void cast_bf16(const float* __restrict__ src,
                          unsigned short* __restrict__ dst, int n4)
{
    int i = blockIdx.x * 256 + threadIdx.x;
    if (i >= n4) return;
    float4 v = *(const float4*)&src[(size_t)i * 4];
    bf16x4 o;
    o[0] = (short)f2bf(v.x); o[1] = (short)f2bf(v.y);
    o[2] = (short)f2bf(v.z); o[3] = (short)f2bf(v.w);
    *(bf16x4*)&dst[(size_t)i * 4] = o;
}

// ---------------------------------------------------------------------------
// fused cast+transpose of all 4 weights: src [2048][C] fp32 -> dst [C][2048].
// blockIdx.y: [0,64) Wq | [64,80) Wk | [80,96) Wv | [96,160) Wo
// ---------------------------------------------------------------------------
__global__ __launch_bounds__(256) void cast_transpose_all(
    const float* __restrict__ Wq, const float* __restrict__ Wk,
    const float* __restrict__ Wv, const float* __restrict__ Wo,
    unsigned short* __restrict__ Wqt, unsigned short* __restrict__ Wkt,
    unsigned short* __restrict__ Wvt, unsigned short* __restrict__ Wot)
{
    __shared__ float T[32][33];
    const int y = blockIdx.y;
    const float* src; unsigned short* dst; int C, bj;
    if (y < 64)      { src = Wq; dst = Wqt; C = 2048; bj = y; }
    else if (y < 80) { src = Wk; dst = Wkt; C = 512;  bj = y - 64; }
    else if (y < 96) { src = Wv; dst = Wvt; C = 512;  bj = y - 80; }
    else             { src = Wo; dst = Wot; C = 2048; bj = y - 96; }

    const int bi = blockIdx.x;
    const int t  = threadIdx.x;
    const int r  = t >> 3, cq = (t & 7) * 4;

    float4 v = *(const float4*)&src[(size_t)(bi * 32 + r) * C + bj * 32 + cq];
    T[r][cq + 0] = v.x; T[r][cq + 1] = v.y;
    T[r][cq + 2] = v.z; T[r][cq + 3] = v.w;
    __syncthreads();

    bf16x4 o;
    o[0] = (short)f2bf(T[cq + 0][r]);
    o[1] = (short)f2bf(T[cq + 1][r]);
    o[2] = (short)f2bf(T[cq + 2][r]);
    o[3] = (short)f2bf(T[cq + 3][r]);
    *(bf16x4*)&dst[(size_t)(bj * 32 + r) * 2048 + bi * 32 + cq] = o;
}

// ---------------------------------------------------------------------------
// Fused QKV projection — 256x256 tile, BK=64, 8-wave (2Mx4N), 8-phase
// counted-vmcnt pipeline (unchanged from R3 — verified; ~98 us is on the
// m102 shape-curve for K=2048 GEMMs, structurally limited).
// ---------------------------------------------------------------------------
__global__ __launch_bounds__(512, 2) void qkv_mfma8(
    const unsigned short* __restrict__ Ah,
    const unsigned short* __restrict__ Wqt,
    const unsigned short* __restrict__ Wkt,
    const unsigned short* __restrict__ Wvt,
    unsigned short* __restrict__ Qh, unsigned short* __restrict__ Kh,
    unsigned short* __restrict__ Vt)
{
    __shared__ __align__(16) unsigned short lds[65536];   // 128 KiB

    const int bid = blockIdx.x;
    const int swz = (bid & 7) * 24 + (bid >> 3);
    const int bm = swz / 12, bn = swz % 12;
    const int m0 = bm * 256, n0 = bn * 256;

    const int tid  = threadIdx.x;
    const int w    = tid >> 6;             // wave 0..7
    const int lane = tid & 63;
    const int lo16 = lane & 15, quad = lane >> 4;
    const int wm   = w >> 2, wn = w & 3;   // 2M x 4N wave grid

    const unsigned short* Bt;
    if (n0 < 2048)      Bt = Wqt + (size_t)n0 * 2048;
    else if (n0 < 2560) Bt = Wkt + (size_t)(n0 - 2048) * 2048;
    else                Bt = Wvt + (size_t)(n0 - 2560) * 2048;
    const unsigned short* Ag   = Ah + (size_t)m0 * 2048;
    const unsigned short* AgH1 = Ag + (size_t)128 * 2048;
    const unsigned short* BtH1 = Bt + (size_t)128 * 2048;

    const int rs   = lane >> 3;                      // 0..7 == grow&7
    const int sce  = (((lane & 7) ^ rs) << 3);       // element col offset
    const int grow = w * 8 + rs;                     // 0..63

    #define STAGE(gb, k0, lb) do {                                          \
        const unsigned short* _g = (gb) + (size_t)grow * 2048 + (k0) + sce; \
        gl_lds16(_g,                     (lb) + w * 512);                   \
        gl_lds16(_g + (size_t)64 * 2048, (lb) + (8 + w) * 512);             \
    } while (0)

    const int swb = (lo16 & 7) << 4;
    const int ac0 = (quad << 4) ^ swb;               // ks=0 (cols 0..31)
    const int ac1 = (64 | (quad << 4)) ^ swb;        // ks=1 (cols 32..63)
    char* ldsb = (char*)lds;
    const int abase = (wm * 128 + lo16) * 128;               // + mf*2048
    const int bbase = (wn * 16 + lo16) * 128 + 32768;        // + frag*8192

    f32x4 acc[8][4];
    #pragma unroll
    for (int mf = 0; mf < 8; ++mf)
        #pragma unroll
        for (int j = 0; j < 4; ++j) acc[mf][j] = (f32x4){0.f, 0.f, 0.f, 0.f};

    bf16x8 a0[4][2], a1[4][2], b0[2][2], b1[2][2];

    #define MM(Aa, Bb, mo, jo)                                               \
        _Pragma("unroll") for (int mf = 0; mf < 4; ++mf)                     \
        _Pragma("unroll") for (int j = 0; j < 2; ++j) {                      \
            acc[(mo)+mf][(jo)+j] = __builtin_amdgcn_mfma_f32_16x16x32_bf16(  \
                Aa[mf][0], Bb[j][0], acc[(mo)+mf][(jo)+j], 0, 0, 0);         \
            acc[(mo)+mf][(jo)+j] = __builtin_amdgcn_mfma_f32_16x16x32_bf16(  \
                Aa[mf][1], Bb[j][1], acc[(mo)+mf][(jo)+j], 0, 0, 0);         \
        }

    STAGE(Bt,   0,  lds + 16384);
    STAGE(BtH1, 0,  lds + 24576);
    STAGE(Ag,   0,  lds + 0);
    STAGE(AgH1, 0,  lds + 8192);
    STAGE(Bt,   64, lds + 32768 + 16384);
    STAGE(BtH1, 64, lds + 32768 + 24576);
    STAGE(Ag,   64, lds + 32768);
    VMW6;
    PH_BAR();

    #define PHASES(p, t)                                                         \
    {   _Pragma("unroll") for (int mf = 0; mf < 4; ++mf) {                       \
            a0[mf][0] = *(const bf16x8*)(ldsb + (p)*65536 + abase + mf*2048 + ac0); \
            a0[mf][1] = *(const bf16x8*)(ldsb + (p)*65536 + abase + mf*2048 + ac1); \
        }                                                                        \
        _Pragma("unroll") for (int j = 0; j < 2; ++j) {                          \
            b0[j][0] = *(const bf16x8*)(ldsb + (p)*65536 + bbase + j*8192 + ac0); \
            b0[j][1] = *(const bf16x8*)(ldsb + (p)*65536 + bbase + j*8192 + ac1); \
        }                                                                        \
        STAGE(AgH1, ((t)+1)*64, lds + ((p)^1)*32768 + 8192);                     \
        PH_BAR(); __builtin_amdgcn_s_setprio(1);                                 \
        MM(a0, b0, 0, 0);                                                        \
        __builtin_amdgcn_s_setprio(0); PH_BAR();                                 \
        _Pragma("unroll") for (int j = 0; j < 2; ++j) {                          \
            b1[j][0] = *(const bf16x8*)(ldsb + (p)*65536 + bbase + (j+2)*8192 + ac0); \
            b1[j][1] = *(const bf16x8*)(ldsb + (p)*65536 + bbase + (j+2)*8192 + ac1); \
        }                                                                        \
        STAGE(Bt, ((t)+2)*64, lds + (p)*32768 + 16384);                          \
        PH_BAR(); __builtin_amdgcn_s_setprio(1);                                 \
        MM(a0, b1, 0, 2);                                                        \
        __builtin_amdgcn_s_setprio(0); PH_BAR();                                 \
        _Pragma("unroll") for (int mf = 0; mf < 4; ++mf) {                       \
            a1[mf][0] = *(const bf16x8*)(ldsb + (p)*65536 + abase + (mf+4)*2048 + ac0); \
            a1[mf][1] = *(const bf16x8*)(ldsb + (p)*65536 + abase + (mf+4)*2048 + ac1); \
        }                                                                        \
        STAGE(BtH1, ((t)+2)*64, lds + (p)*32768 + 24576);                        \
        PH_BAR(); __builtin_amdgcn_s_setprio(1);                                 \
        MM(a1, b0, 4, 0);                                                        \
        __builtin_amdgcn_s_setprio(0); PH_BAR();                                 \
        STAGE(Ag, ((t)+2)*64, lds + (p)*32768);                                  \
        PH_BAR(); __builtin_amdgcn_s_setprio(1);                                 \
        MM(a1, b1, 4, 2);                                                        \
        __builtin_amdgcn_s_setprio(0);                                           \
        VMW6;                                                                    \
        PH_BAR();                                                                \
    }

    for (int it = 0; it < 16; ++it) {
        const int t = 2 * it;
        PHASES(0, t);
        PHASES(1, t + 1);
    }

    // Drain ALL outstanding LDS-DMA before epilogue (retire hazard + V path
    // reuses the staging LDS as its transpose buffer).
    VMW0;
    PH_BAR();

    const int bb = m0 >> 11;        // tile never crosses batch
    const int s0loc = m0 & 2047;

    if (n0 < 2560) {
        const bool isQ = (n0 < 2048);
        const int h0 = isQ ? (n0 >> 7) : ((n0 - 2048) >> 7);
        const float post = isQ ? QSCALE_LOG2E : 1.0f;
        unsigned short* db[2];
        #pragma unroll
        for (int hp = 0; hp < 2; ++hp)
            db[hp] = isQ
                ? Qh + (((size_t)bb * H_   + h0 + hp) * S_) * HD_
                : Kh + (((size_t)bb * KVH_ + h0 + hp) * S_) * HD_;
        const int d = wn * 16 + lo16;                    // 0..63
        const float inv = exp2f(-(float)d * 0.20761871093344086f);
        #pragma unroll
        for (int mf = 0; mf < 8; ++mf) {
            #pragma unroll
            for (int r = 0; r < 4; ++r) {
                int s = s0loc + wm * 128 + mf * 16 + quad * 4 + r;
                float sn, c;
                sincosf((float)s * inv, &sn, &c);
                #pragma unroll
                for (int hp = 0; hp < 2; ++hp) {
                    float lo = acc[mf][2 * hp + 0][r];
                    float hi = acc[mf][2 * hp + 1][r];
                    unsigned short* drow = db[hp] + (size_t)s * HD_;
                    drow[d]      = f2bf((lo * c - hi * sn) * post);
                    drow[d + 64] = f2bf((hi * c + lo * sn) * post);
                }
            }
        }
    } else {
        const int g0 = (n0 - 2560) >> 7;
        unsigned short* Ts = lds;                        // [128][264]
        const int d = wn * 16 + lo16;
        #pragma unroll
        for (int hp = 0; hp < 2; ++hp) {
            if (hp) PH_BAR();                            // stores of hp=0 done
            #pragma unroll
            for (int mf = 0; mf < 8; ++mf) {
                int ml = wm * 128 + mf * 16 + quad * 4;
                bf16x4 v0, v1;
                #pragma unroll
                for (int r = 0; r < 4; ++r) {
                    v0[r] = (short)f2bf(acc[mf][2 * hp + 0][r]);
                    v1[r] = (short)f2bf(acc[mf][2 * hp + 1][r]);
                }
                *(bf16x4*)&Ts[(size_t)d        * 264 + ml] = v0;
                *(bf16x4*)&Ts[(size_t)(d + 64) * 264 + ml] = v1;
            }
            PH_BAR();
            unsigned short* dstb = Vt + (((size_t)bb * KVH_ + g0 + hp) * HD_) * S_ + s0loc;
            #pragma unroll
            for (int itb = 0; itb < 8; ++itb) {
                int dd = itb * 16 + (tid >> 5);
                int ch = (tid & 31) * 8;
                *(bf16x8*)(dstb + (size_t)dd * S_ + ch) =
                    *(const bf16x8*)&Ts[(size_t)dd * 264 + ch];
            }
        }
    }
    #undef PHASES
    #undef MM
    #undef STAGE
}

// ---------------------------------------------------------------------------
// Flash attention v10: v8 + within-wave MFMA/VALU overlap (T15 mechanism).
// R6/R8/R9 proved barrier scheme, wave count, and conflicts<10M don't move
// time: the limiter is the per-wave serial chain QK->softmax->PV (all waves
// in the same phase -> pipes never overlap). Fix: double-buffer Ks/Vs
// (v8's exact padded layouts x2) and HOIST QK(t+1) before softmax(t)+PV(t):
// the wave issues QK(t+1)'s 16 MFMAs, then softmax(t)'s VALU runs UNDER
// them (separate pipes, m114), then PV(t). Barriers/masks/staging/epilogue
// identical to v8. LDS 88 KiB -> 1 block/CU (R6-vs-R8: occupancy halving
// costs ~0-3 us; the VALU hide is worth ~15-20).
// ---------------------------------------------------------------------------
__global__ __launch_bounds__(512, 4) void flash_attn_mfma(
    const unsigned short* __restrict__ Qh,
    const unsigned short* __restrict__ Kh,
    const unsigned short* __restrict__ Vt,
    unsigned short* __restrict__ attb)
{
    const int bh   = blockIdx.x;           // 0..31
    const int yy   = blockIdx.y;           // 0..15
    const int qt   = (yy < 8) ? (15 - yy) : (yy - 8);
    const int b    = bh >> 4, h = bh & 15;
    const int g    = h >> 2;
    const int tid  = threadIdx.x;
    const int w    = tid >> 6;             // wave 0..7
    const int lane = tid & 63;
    const int lo16 = lane & 15;
    const int quad = lane >> 4;

    const unsigned short* Qb = Qh + (((size_t)b * H_   + h) * S_) * HD_;
    const unsigned short* Kb = Kh + (((size_t)b * KVH_ + g) * S_) * HD_;
    const unsigned short* Vb = Vt + (((size_t)b * KVH_ + g) * HD_) * S_;

    __shared__ __align__(16) unsigned short Ks[2][64][136];
    __shared__ __align__(16) unsigned short Vs[2][128][72];
    __shared__ __align__(16) unsigned short Ps[8][16][72];

    const int q0 = qt * 128;
    const int qw = q0 + w * 16;            // wave's 16 q-rows

    bf16x8 qf[4];
    #pragma unroll
    for (int kc = 0; kc < 4; ++kc)
        qf[kc] = *(const bf16x8*)(Qb + (size_t)(qw + lo16) * HD_ + kc * 32 + quad * 8);

    f32x4 o[8];
    #pragma unroll
    for (int n = 0; n < 8; ++n) o[n] = (f32x4){0.f, 0.f, 0.f, 0.f};
    float l_loc[4];
    #pragma unroll
    for (int r = 0; r < 4; ++r) l_loc[r] = 0.0f;

    // staging map (512 threads): K rows 32i+kr (kr 0..31), unit kcu 0..15;
    // V rows 64i+vr (vr 0..63), unit vcu 0..7. Plain unit addressing —
    // padded row stride provides the bank rotation.
    const int kr  = tid >> 4, kcu = tid & 15;
    const int vr  = tid >> 3, vcu = tid & 7;

    bf16x8 kreg[2], vreg[2];

    // ---- prologue: stage tiles 0 and 1 (ktend >= 1 always) ----
    #pragma unroll
    for (int i = 0; i < 2; ++i) {
        kreg[i] = *(const bf16x8*)(Kb + (size_t)(32 * i + kr) * HD_ + kcu * 8);
        vreg[i] = *(const bf16x8*)(Vb + (size_t)(64 * i + vr) * S_ + vcu * 8);
    }
    #pragma unroll
    for (int i = 0; i < 2; ++i) {
        *(bf16x8*)&Ks[0][32 * i + kr][kcu * 8] = kreg[i];
        *(bf16x8*)&Vs[0][64 * i + vr][vcu * 8] = vreg[i];
    }
    #pragma unroll
    for (int i = 0; i < 2; ++i) {
        kreg[i] = *(const bf16x8*)(Kb + (size_t)(64 + 32 * i + kr) * HD_ + kcu * 8);
        vreg[i] = *(const bf16x8*)(Vb + (size_t)(64 * i + vr) * S_ + 64 + vcu * 8);
    }
    #pragma unroll
    for (int i = 0; i < 2; ++i) {
        *(bf16x8*)&Ks[1][32 * i + kr][kcu * 8] = kreg[i];
        *(bf16x8*)&Vs[1][64 * i + vr][vcu * 8] = vreg[i];
    }
    asm volatile("s_waitcnt lgkmcnt(0)" ::: "memory");
    asm volatile("s_barrier" ::: "memory");

    // ---- QK(0) ----
    f32x4 scC[4];
    #pragma unroll
    for (int cb = 0; cb < 4; ++cb) scC[cb] = (f32x4){0.f, 0.f, 0.f, 0.f};
    #pragma unroll
    for (int kc = 0; kc < 4; ++kc)
        #pragma unroll
        for (int cb = 0; cb < 4; ++cb) {
            bf16x8 kf = *(const bf16x8*)&Ks[0][cb * 16 + lo16][kc * 32 + quad * 8];
            scC[cb] = __builtin_amdgcn_mfma_f32_16x16x32_bf16(
                qf[kc], kf, scC[cb], 0, 0, 0);
        }

    const int ktend = 2 * qt + 1;          // block's last kv-tile
    for (int kt = 0; kt <= ktend; ++kt) {
        const int p = kt & 1;

        // ---- QK(t+1) hoisted: issues MFMAs the softmax below hides under ----
        f32x4 scN[4];
        #pragma unroll
        for (int cb = 0; cb < 4; ++cb) scN[cb] = (f32x4){0.f, 0.f, 0.f, 0.f};
        if (kt < ktend) {
            #pragma unroll
            for (int kc = 0; kc < 4; ++kc)
                #pragma unroll
                for (int cb = 0; cb < 4; ++cb) {
                    bf16x8 kf = *(const bf16x8*)&Ks[p ^ 1][cb * 16 + lo16][kc * 32 + quad * 8];
                    scN[cb] = __builtin_amdgcn_mfma_f32_16x16x32_bf16(
                        qf[kc], kf, scN[cb], 0, 0, 0);
                }
        }

        // ---- issue t+2 global loads (hide under softmax+PV) ----
        if (kt + 2 <= ktend) {
            const int k0n = (kt + 2) * 64;
            #pragma unroll
            for (int i = 0; i < 2; ++i) {
                kreg[i] = *(const bf16x8*)(Kb + (size_t)(k0n + 32 * i + kr) * HD_ + kcu * 8);
                vreg[i] = *(const bf16x8*)(Vb + (size_t)(64 * i + vr) * S_ + k0n + vcu * 8);
            }
        }

        // ---- softmax(t) + PV(t) (VALU under QK(t+1)'s MFMAs) ----
        if (w >= 4 || kt < ktend) {
            const int k0 = kt * 64;
            const bool masked = (w < 4) ? (kt == 2 * qt) : (kt == ktend);
            if (masked) {
                #pragma unroll
                for (int r = 0; r < 4; ++r) {
                    const int row = qw + quad * 4 + r;
                    float lacc = 0.0f;
                    #pragma unroll
                    for (int cb = 0; cb < 4; ++cb) {
                        float xv = scC[cb][r];
                        if ((k0 + cb * 16 + lo16) > row) xv = -1e30f;
                        float pp = exp2f(xv);
                        lacc += pp;
                        Ps[w][quad * 4 + r][cb * 16 + lo16] = f2bf_fast(pp);
                    }
                    l_loc[r] += lacc;
                }
            } else {
                #pragma unroll
                for (int r = 0; r < 4; ++r) {
                    float lacc = 0.0f;
                    #pragma unroll
                    for (int cb = 0; cb < 4; ++cb) {
                        float pp = exp2f(scC[cb][r]);
                        lacc += pp;
                        Ps[w][quad * 4 + r][cb * 16 + lo16] = f2bf_fast(pp);
                    }
                    l_loc[r] += lacc;
                }
            }

            #pragma unroll
            for (int kc = 0; kc < 2; ++kc) {
                bf16x8 pf = *(const bf16x8*)&Ps[w][lo16][kc * 32 + quad * 8];
                #pragma unroll
                for (int n = 0; n < 8; ++n) {
                    bf16x8 vf = *(const bf16x8*)&Vs[p][n * 16 + lo16][kc * 32 + quad * 8];
                    o[n] = __builtin_amdgcn_mfma_f32_16x16x32_bf16(
                        pf, vf, o[n], 0, 0, 0);
                }
            }
        }

        // barrier A: all waves done with Vs[p] (PV) before it's overwritten
        asm volatile("s_barrier" ::: "memory");
        if (kt + 2 <= ktend) {
            #pragma unroll
            for (int i = 0; i < 2; ++i) {
                *(bf16x8*)&Ks[p][32 * i + kr][kcu * 8] = kreg[i];
                *(bf16x8*)&Vs[p][64 * i + vr][vcu * 8] = vreg[i];
            }
        }
        // barrier B: t+2 writes visible; vmcnt untouched elsewhere
        asm volatile("s_waitcnt lgkmcnt(0)" ::: "memory");
        asm volatile("s_barrier" ::: "memory");

        // rotate (static copy — no runtime-indexed arrays)
        #pragma unroll
        for (int cb = 0; cb < 4; ++cb) scC[cb] = scN[cb];
    }

    #pragma unroll
    for (int r = 0; r < 4; ++r) {
        float l = l_loc[r];
        l += __shfl_xor(l, 1);
        l += __shfl_xor(l, 2);
        l += __shfl_xor(l, 4);
        l += __shfl_xor(l, 8);
        float invl = 1.0f / l;
        int srow = qw + quad * 4 + r;
        unsigned short* dst = attb + ((size_t)b * S_ + srow) * D_ + h * HD_;
        #pragma unroll
        for (int n = 0; n < 8; ++n)
            dst[n * 16 + lo16] = f2bf(o[n][r] * invl);
    }
}

// ---------------------------------------------------------------------------
// Output projection — 256x128 tile, BK=64, 8-wave (2Mx4N), 8-phase
// counted-vmcnt pipeline (unchanged from R4 — verified).
// ---------------------------------------------------------------------------
__global__ __launch_bounds__(512, 2) void out_mfma8(
    const unsigned short* __restrict__ Ah,
    const unsigned short* __restrict__ Wot,
    float* __restrict__ C)
{
    __shared__ __align__(16) unsigned short lds[49152];   // 96 KiB

    const int bid = blockIdx.x;
    const int swz = (bid & 7) * 32 + (bid >> 3);
    const int bm = swz >> 4, bn = swz & 15;
    const int m0 = bm * 256, n0 = bn * 128;

    const int tid  = threadIdx.x;
    const int w    = tid >> 6;             // wave 0..7
    const int lane = tid & 63;
    const int lo16 = lane & 15, quad = lane >> 4;
    const int wm   = w >> 2, wn = w & 3;   // 2M x 4N wave grid

    const unsigned short* Ag   = Ah  + (size_t)m0 * 2048;
    const unsigned short* AgH1 = Ag  + (size_t)128 * 2048;
    const unsigned short* Bt   = Wot + (size_t)n0 * 2048;

    const int rs   = lane >> 3;
    const int sce  = (((lane & 7) ^ rs) << 3);
    const int grow = w * 8 + rs;

    #define OSTAGE(gb, k0, lb) do {                                         \
        const unsigned short* _g = (gb) + (size_t)grow * 2048 + (k0) + sce; \
        gl_lds16(_g,                     (lb) + w * 512);                   \
        gl_lds16(_g + (size_t)64 * 2048, (lb) + (8 + w) * 512);             \
    } while (0)

    const int swb = (lo16 & 7) << 4;
    const int ac0 = (quad << 4) ^ swb;
    const int ac1 = (64 | (quad << 4)) ^ swb;
    char* ldsb = (char*)lds;
    const int abase = (wm * 128 + lo16) * 128;               // + mf*2048
    const int bbase = (wn * 32 + lo16) * 128 + 32768;        // + j*2048

    f32x4 acc[8][2];
    #pragma unroll
    for (int mf = 0; mf < 8; ++mf)
        #pragma unroll
        for (int j = 0; j < 2; ++j) acc[mf][j] = (f32x4){0.f, 0.f, 0.f, 0.f};

    bf16x8 a0[4][2], a1[4][2], bb[2][2];

    #define OMM(Aa, mo, j)                                                   \
        _Pragma("unroll") for (int mf = 0; mf < 4; ++mf) {                   \
            acc[(mo)+mf][j] = __builtin_amdgcn_mfma_f32_16x16x32_bf16(       \
                Aa[mf][0], bb[j][0], acc[(mo)+mf][j], 0, 0, 0);              \
            acc[(mo)+mf][j] = __builtin_amdgcn_mfma_f32_16x16x32_bf16(       \
                Aa[mf][1], bb[j][1], acc[(mo)+mf][j], 0, 0, 0);              \
        }

    OSTAGE(Bt,   0,  lds + 16384);
    OSTAGE(Ag,   0,  lds + 0);
    OSTAGE(AgH1, 0,  lds + 8192);
    OSTAGE(Bt,   64, lds + 24576 + 16384);
    OSTAGE(Ag,   64, lds + 24576);
    VMW4;
    PH_BAR();

    #define OPH(p, t)                                                            \
    {   _Pragma("unroll") for (int mf = 0; mf < 4; ++mf) {                       \
            a0[mf][0] = *(const bf16x8*)(ldsb + (p)*49152 + abase + mf*2048 + ac0); \
            a0[mf][1] = *(const bf16x8*)(ldsb + (p)*49152 + abase + mf*2048 + ac1); \
        }                                                                        \
        _Pragma("unroll") for (int j = 0; j < 2; ++j) {                          \
            bb[j][0] = *(const bf16x8*)(ldsb + (p)*49152 + bbase + j*2048 + ac0); \
            bb[j][1] = *(const bf16x8*)(ldsb + (p)*49152 + bbase + j*2048 + ac1); \
        }                                                                        \
        OSTAGE(AgH1, ((t)+1)*64, lds + ((p)^1)*24576 + 8192);                    \
        PH_BAR(); __builtin_amdgcn_s_setprio(1);                                 \
        OMM(a0, 0, 0);                                                           \
        __builtin_amdgcn_s_setprio(0); PH_BAR();                                 \
        OSTAGE(Bt, ((t)+2)*64, lds + (p)*24576 + 16384);                         \
        PH_BAR(); __builtin_amdgcn_s_setprio(1);                                 \
        OMM(a0, 0, 1);                                                           \
        __builtin_amdgcn_s_setprio(0); PH_BAR();                                 \
        _Pragma("unroll") for (int mf = 0; mf < 4; ++mf) {                       \
            a1[mf][0] = *(const bf16x8*)(ldsb + (p)*49152 + abase + (mf+4)*2048 + ac0); \
            a1[mf][1] = *(const bf16x8*)(ldsb + (p)*49152 + abase + (mf+4)*2048 + ac1); \
        }                                                                        \
        PH_BAR(); __builtin_amdgcn_s_setprio(1);                                 \
        OMM(a1, 4, 0);                                                           \
        __builtin_amdgcn_s_setprio(0); PH_BAR();                                 \
        OSTAGE(Ag, ((t)+2)*64, lds + (p)*24576);                                 \
        PH_BAR(); __builtin_amdgcn_s_setprio(1);                                 \
        OMM(a1, 4, 1);                                                           \
        __builtin_amdgcn_s_setprio(0);                                           \
        VMW4;                                                                    \
        PH_BAR();                                                                \
    }

    for (int it = 0; it < 16; ++it) {
        const int t = 2 * it;
        OPH(0, t);
        OPH(1, t + 1);
    }

    VMW0;

    #pragma unroll
    for (int mf = 0; mf < 8; ++mf)
        #pragma unroll
        for (int r = 0; r < 4; ++r) {
            size_t m = (size_t)(m0 + wm * 128 + mf * 16 + quad * 4 + r);
            #pragma unroll
            for (int j = 0; j < 2; ++j)
                C[m * 2048 + n0 + wn * 32 + j * 16 + lo16] = acc[mf][j][r];
        }
    #undef OPH
    #undef OMM
    #undef OSTAGE
}

// ---------------------------------------------------------------------------
// Workspace layout (bf16 shorts), total 60 MB:
//   xh/attb : 0    .. 16 MB   (xh dead after qkv -> attb aliases it)
//   Wqt     : 16   .. 24 MB
//   Wkt     : 24   .. 26 MB
//   Wvt     : 26   .. 28 MB
//   Wot     : 28   .. 36 MB
//   Qh      : 36   .. 52 MB
//   Kh      : 52   .. 56 MB
//   Vt      : 56   .. 60 MB
// ---------------------------------------------------------------------------
extern "C" void kernel_launch(void* const* d_in, const int* in_sizes, int n_in,
                              void* d_out, int out_size, void* d_ws, size_t ws_size,
                              hipStream_t stream)
{
    const float* x  = (const float*)d_in[0];
    const float* Wq = (const float*)d_in[1];
    const float* Wk = (const float*)d_in[2];
    const float* Wv = (const float*)d_in[3];
    const float* Wo = (const float*)d_in[4];
    float* out = (float*)d_out;

    unsigned short* xh  = (unsigned short*)d_ws;
    unsigned short* Wqt = xh  + (size_t)4096 * 2048;
    unsigned short* Wkt = Wqt + (size_t)2048 * 2048;
    unsigned short* Wvt = Wkt + (size_t)512 * 2048;
    unsigned short* Wot = Wvt + (size_t)512 * 2048;
    unsigned short* Qh  = Wot + (size_t)2048 * 2048;
    unsigned short* Kh  = Qh  + (size_t)B_ * H_   * S_ * HD_;
    unsigned short* Vt  = Kh  + (size_t)B_ * KVH_ * S_ * HD_;
    unsigned short* attb= xh;   // reuse: xh dead after qkv_mfma8

    cast_bf16<<<(4096 * 2048 / 4 + 255) / 256, 256, 0, stream>>>(x, xh, 4096 * 2048 / 4);
    cast_transpose_all<<<dim3(64, 160), 256, 0, stream>>>(Wq, Wk, Wv, Wo, Wqt, Wkt, Wvt, Wot);

    qkv_mfma8<<<192, 512, 0, stream>>>(xh, Wqt, Wkt, Wvt, Qh, Kh, Vt);

    flash_attn_mfma<<<dim3(32, 16), 512, 0, stream>>>(Qh, Kh, Vt, attb);

    out_mfma8<<<256, 512, 0, stream>>>(attb, Wot, out);
}

// Round 13
// 273.573 us; speedup vs baseline: 1.0911x; 1.0911x over previous
//
#include <hip/hip_runtime.h>
#include <math.h>

#define B_   2
#define S_   2048
#define D_   2048
#define H_   16
#define KVH_ 4
#define HD_  128
#define REP_ 4

typedef __attribute__((ext_vector_type(8))) short bf16x8;
typedef __attribute__((ext_vector_type(4))) short bf16x4;
typedef __attribute__((ext_vector_type(4))) float f32x4;

// 1/sqrt(128) * log2(e): folded into Q so flash scores are base-2 pre-scaled
#define QSCALE_LOG2E 0.1275266977097153f

__device__ __forceinline__ unsigned short f2bf(float x) {
    union { float f; unsigned u; } v; v.f = x;
    unsigned r = v.u + 0x7FFF + ((v.u >> 16) & 1);   // RNE
    return (unsigned short)(r >> 16);
}

// cheap round-half-up bf16 (used only for P; bias cancels in p/sum(p))
__device__ __forceinline__ unsigned short f2bf_fast(float x) {
    union { float f; unsigned u; } v; v.f = x;
    return (unsigned short)((v.u + 0x8000) >> 16);
}

// async global->LDS, 16B per lane; LDS dest is wave-uniform base + lane*16
__device__ __forceinline__ void gl_lds16(const unsigned short* g, unsigned short* l) {
    __builtin_amdgcn_global_load_lds(
        (const __attribute__((address_space(1))) unsigned int*)g,
        (__attribute__((address_space(3))) unsigned int*)l,
        16, 0, 0);
}

#define PH_BAR() do { asm volatile("" ::: "memory"); \
                      __builtin_amdgcn_s_barrier();  \
                      asm volatile("" ::: "memory"); } while (0)
#define VMW6 asm volatile("s_waitcnt vmcnt(6)" ::: "memory")
#define VMW4 asm volatile("s_waitcnt vmcnt(4)" ::: "memory")
#define VMW0 asm volatile("s_waitcnt vmcnt(0)" ::: "memory")

// ---------------------------------------------------------------------------
// cast fp32 -> bf16 (elementwise)
// ---------------------------------------------------------------------------
__global__ void cast_bf16(const float* __restrict__ src,
                          unsigned short* __restrict__ dst, int n4)
{
    int i = blockIdx.x * 256 + threadIdx.x;
    if (i >= n4) return;
    float4 v = *(const float4*)&src[(size_t)i * 4];
    bf16x4 o;
    o[0] = (short)f2bf(v.x); o[1] = (short)f2bf(v.y);
    o[2] = (short)f2bf(v.z); o[3] = (short)f2bf(v.w);
    *(bf16x4*)&dst[(size_t)i * 4] = o;
}

// ---------------------------------------------------------------------------
// fused cast+transpose of all 4 weights: src [2048][C] fp32 -> dst [C][2048].
// blockIdx.y: [0,64) Wq | [64,80) Wk | [80,96) Wv | [96,160) Wo
// ---------------------------------------------------------------------------
__global__ __launch_bounds__(256) void cast_transpose_all(
    const float* __restrict__ Wq, const float* __restrict__ Wk,
    const float* __restrict__ Wv, const float* __restrict__ Wo,
    unsigned short* __restrict__ Wqt, unsigned short* __restrict__ Wkt,
    unsigned short* __restrict__ Wvt, unsigned short* __restrict__ Wot)
{
    __shared__ float T[32][33];
    const int y = blockIdx.y;
    const float* src; unsigned short* dst; int C, bj;
    if (y < 64)      { src = Wq; dst = Wqt; C = 2048; bj = y; }
    else if (y < 80) { src = Wk; dst = Wkt; C = 512;  bj = y - 64; }
    else if (y < 96) { src = Wv; dst = Wvt; C = 512;  bj = y - 80; }
    else             { src = Wo; dst = Wot; C = 2048; bj = y - 96; }

    const int bi = blockIdx.x;
    const int t  = threadIdx.x;
    const int r  = t >> 3, cq = (t & 7) * 4;

    float4 v = *(const float4*)&src[(size_t)(bi * 32 + r) * C + bj * 32 + cq];
    T[r][cq + 0] = v.x; T[r][cq + 1] = v.y;
    T[r][cq + 2] = v.z; T[r][cq + 3] = v.w;
    __syncthreads();

    bf16x4 o;
    o[0] = (short)f2bf(T[cq + 0][r]);
    o[1] = (short)f2bf(T[cq + 1][r]);
    o[2] = (short)f2bf(T[cq + 2][r]);
    o[3] = (short)f2bf(T[cq + 3][r]);
    *(bf16x4*)&dst[(size_t)(bj * 32 + r) * 2048 + bi * 32 + cq] = o;
}

// ---------------------------------------------------------------------------
// Fused QKV projection — 256x256 tile, BK=64, 8-wave (2Mx4N), 8-phase
// counted-vmcnt pipeline (verified R3-R11; ~98 us is on the m102
// shape-curve for K=2048 GEMMs — structurally limited).
// ---------------------------------------------------------------------------
__global__ __launch_bounds__(512, 2) void qkv_mfma8(
    const unsigned short* __restrict__ Ah,
    const unsigned short* __restrict__ Wqt,
    const unsigned short* __restrict__ Wkt,
    const unsigned short* __restrict__ Wvt,
    unsigned short* __restrict__ Qh, unsigned short* __restrict__ Kh,
    unsigned short* __restrict__ Vt)
{
    __shared__ __align__(16) unsigned short lds[65536];   // 128 KiB

    const int bid = blockIdx.x;
    const int swz = (bid & 7) * 24 + (bid >> 3);
    const int bm = swz / 12, bn = swz % 12;
    const int m0 = bm * 256, n0 = bn * 256;

    const int tid  = threadIdx.x;
    const int w    = tid >> 6;             // wave 0..7
    const int lane = tid & 63;
    const int lo16 = lane & 15, quad = lane >> 4;
    const int wm   = w >> 2, wn = w & 3;   // 2M x 4N wave grid

    const unsigned short* Bt;
    if (n0 < 2048)      Bt = Wqt + (size_t)n0 * 2048;
    else if (n0 < 2560) Bt = Wkt + (size_t)(n0 - 2048) * 2048;
    else                Bt = Wvt + (size_t)(n0 - 2560) * 2048;
    const unsigned short* Ag   = Ah + (size_t)m0 * 2048;
    const unsigned short* AgH1 = Ag + (size_t)128 * 2048;
    const unsigned short* BtH1 = Bt + (size_t)128 * 2048;

    const int rs   = lane >> 3;                      // 0..7 == grow&7
    const int sce  = (((lane & 7) ^ rs) << 3);       // element col offset
    const int grow = w * 8 + rs;                     // 0..63

    #define STAGE(gb, k0, lb) do {                                          \
        const unsigned short* _g = (gb) + (size_t)grow * 2048 + (k0) + sce; \
        gl_lds16(_g,                     (lb) + w * 512);                   \
        gl_lds16(_g + (size_t)64 * 2048, (lb) + (8 + w) * 512);             \
    } while (0)

    const int swb = (lo16 & 7) << 4;
    const int ac0 = (quad << 4) ^ swb;               // ks=0 (cols 0..31)
    const int ac1 = (64 | (quad << 4)) ^ swb;        // ks=1 (cols 32..63)
    char* ldsb = (char*)lds;
    const int abase = (wm * 128 + lo16) * 128;               // + mf*2048
    const int bbase = (wn * 16 + lo16) * 128 + 32768;        // + frag*8192

    f32x4 acc[8][4];
    #pragma unroll
    for (int mf = 0; mf < 8; ++mf)
        #pragma unroll
        for (int j = 0; j < 4; ++j) acc[mf][j] = (f32x4){0.f, 0.f, 0.f, 0.f};

    bf16x8 a0[4][2], a1[4][2], b0[2][2], b1[2][2];

    #define MM(Aa, Bb, mo, jo)                                               \
        _Pragma("unroll") for (int mf = 0; mf < 4; ++mf)                     \
        _Pragma("unroll") for (int j = 0; j < 2; ++j) {                      \
            acc[(mo)+mf][(jo)+j] = __builtin_amdgcn_mfma_f32_16x16x32_bf16(  \
                Aa[mf][0], Bb[j][0], acc[(mo)+mf][(jo)+j], 0, 0, 0);         \
            acc[(mo)+mf][(jo)+j] = __builtin_amdgcn_mfma_f32_16x16x32_bf16(  \
                Aa[mf][1], Bb[j][1], acc[(mo)+mf][(jo)+j], 0, 0, 0);         \
        }

    STAGE(Bt,   0,  lds + 16384);
    STAGE(BtH1, 0,  lds + 24576);
    STAGE(Ag,   0,  lds + 0);
    STAGE(AgH1, 0,  lds + 8192);
    STAGE(Bt,   64, lds + 32768 + 16384);
    STAGE(BtH1, 64, lds + 32768 + 24576);
    STAGE(Ag,   64, lds + 32768);
    VMW6;
    PH_BAR();

    #define PHASES(p, t)                                                         \
    {   _Pragma("unroll") for (int mf = 0; mf < 4; ++mf) {                       \
            a0[mf][0] = *(const bf16x8*)(ldsb + (p)*65536 + abase + mf*2048 + ac0); \
            a0[mf][1] = *(const bf16x8*)(ldsb + (p)*65536 + abase + mf*2048 + ac1); \
        }                                                                        \
        _Pragma("unroll") for (int j = 0; j < 2; ++j) {                          \
            b0[j][0] = *(const bf16x8*)(ldsb + (p)*65536 + bbase + j*8192 + ac0); \
            b0[j][1] = *(const bf16x8*)(ldsb + (p)*65536 + bbase + j*8192 + ac1); \
        }                                                                        \
        STAGE(AgH1, ((t)+1)*64, lds + ((p)^1)*32768 + 8192);                     \
        PH_BAR(); __builtin_amdgcn_s_setprio(1);                                 \
        MM(a0, b0, 0, 0);                                                        \
        __builtin_amdgcn_s_setprio(0); PH_BAR();                                 \
        _Pragma("unroll") for (int j = 0; j < 2; ++j) {                          \
            b1[j][0] = *(const bf16x8*)(ldsb + (p)*65536 + bbase + (j+2)*8192 + ac0); \
            b1[j][1] = *(const bf16x8*)(ldsb + (p)*65536 + bbase + (j+2)*8192 + ac1); \
        }                                                                        \
        STAGE(Bt, ((t)+2)*64, lds + (p)*32768 + 16384);                          \
        PH_BAR(); __builtin_amdgcn_s_setprio(1);                                 \
        MM(a0, b1, 0, 2);                                                        \
        __builtin_amdgcn_s_setprio(0); PH_BAR();                                 \
        _Pragma("unroll") for (int mf = 0; mf < 4; ++mf) {                       \
            a1[mf][0] = *(const bf16x8*)(ldsb + (p)*65536 + abase + (mf+4)*2048 + ac0); \
            a1[mf][1] = *(const bf16x8*)(ldsb + (p)*65536 + abase + (mf+4)*2048 + ac1); \
        }                                                                        \
        STAGE(BtH1, ((t)+2)*64, lds + (p)*32768 + 24576);                        \
        PH_BAR(); __builtin_amdgcn_s_setprio(1);                                 \
        MM(a1, b0, 4, 0);                                                        \
        __builtin_amdgcn_s_setprio(0); PH_BAR();                                 \
        STAGE(Ag, ((t)+2)*64, lds + (p)*32768);                                  \
        PH_BAR(); __builtin_amdgcn_s_setprio(1);                                 \
        MM(a1, b1, 4, 2);                                                        \
        __builtin_amdgcn_s_setprio(0);                                           \
        VMW6;                                                                    \
        PH_BAR();                                                                \
    }

    for (int it = 0; it < 16; ++it) {
        const int t = 2 * it;
        PHASES(0, t);
        PHASES(1, t + 1);
    }

    // Drain ALL outstanding LDS-DMA before epilogue (retire hazard + V path
    // reuses the staging LDS as its transpose buffer).
    VMW0;
    PH_BAR();

    const int bb = m0 >> 11;        // tile never crosses batch
    const int s0loc = m0 & 2047;

    if (n0 < 2560) {
        const bool isQ = (n0 < 2048);
        const int h0 = isQ ? (n0 >> 7) : ((n0 - 2048) >> 7);
        const float post = isQ ? QSCALE_LOG2E : 1.0f;
        unsigned short* db[2];
        #pragma unroll
        for (int hp = 0; hp < 2; ++hp)
            db[hp] = isQ
                ? Qh + (((size_t)bb * H_   + h0 + hp) * S_) * HD_
                : Kh + (((size_t)bb * KVH_ + h0 + hp) * S_) * HD_;
        const int d = wn * 16 + lo16;                    // 0..63
        const float inv = exp2f(-(float)d * 0.20761871093344086f);
        #pragma unroll
        for (int mf = 0; mf < 8; ++mf) {
            #pragma unroll
            for (int r = 0; r < 4; ++r) {
                int s = s0loc + wm * 128 + mf * 16 + quad * 4 + r;
                float sn, c;
                sincosf((float)s * inv, &sn, &c);
                #pragma unroll
                for (int hp = 0; hp < 2; ++hp) {
                    float lo = acc[mf][2 * hp + 0][r];
                    float hi = acc[mf][2 * hp + 1][r];
                    unsigned short* drow = db[hp] + (size_t)s * HD_;
                    drow[d]      = f2bf((lo * c - hi * sn) * post);
                    drow[d + 64] = f2bf((hi * c + lo * sn) * post);
                }
            }
        }
    } else {
        const int g0 = (n0 - 2560) >> 7;
        unsigned short* Ts = lds;                        // [128][264]
        const int d = wn * 16 + lo16;
        #pragma unroll
        for (int hp = 0; hp < 2; ++hp) {
            if (hp) PH_BAR();                            // stores of hp=0 done
            #pragma unroll
            for (int mf = 0; mf < 8; ++mf) {
                int ml = wm * 128 + mf * 16 + quad * 4;
                bf16x4 v0, v1;
                #pragma unroll
                for (int r = 0; r < 4; ++r) {
                    v0[r] = (short)f2bf(acc[mf][2 * hp + 0][r]);
                    v1[r] = (short)f2bf(acc[mf][2 * hp + 1][r]);
                }
                *(bf16x4*)&Ts[(size_t)d        * 264 + ml] = v0;
                *(bf16x4*)&Ts[(size_t)(d + 64) * 264 + ml] = v1;
            }
            PH_BAR();
            unsigned short* dstb = Vt + (((size_t)bb * KVH_ + g0 + hp) * HD_) * S_ + s0loc;
            #pragma unroll
            for (int itb = 0; itb < 8; ++itb) {
                int dd = itb * 16 + (tid >> 5);
                int ch = (tid & 31) * 8;
                *(bf16x8*)(dstb + (size_t)dd * S_ + ch) =
                    *(const bf16x8*)&Ts[(size_t)dd * 264 + ch];
            }
        }
    }
    #undef PHASES
    #undef MM
    #undef STAGE
}

// ---------------------------------------------------------------------------
// Flash attention v8 (best-measured variant, 75.2 us): 8 waves x 16 q-rows,
// plain padded LDS, plain-barrier + lgkm-only-barrier per tile, register
// prefetch. Six levers (barrier scheme, wave count, swizzle, drift, QK-hoist,
// occupancy) all measured neutral-or-negative vs this structure; its plateau
// is the per-wave serial QK->softmax->PV chain (all pipes <30%) — only the
// full HK/AITER co-designed schedule moves past it.
// ---------------------------------------------------------------------------
__global__ __launch_bounds__(512, 4) void flash_attn_mfma(
    const unsigned short* __restrict__ Qh,
    const unsigned short* __restrict__ Kh,
    const unsigned short* __restrict__ Vt,
    unsigned short* __restrict__ attb)
{
    const int bh   = blockIdx.x;           // 0..31
    const int yy   = blockIdx.y;           // 0..15
    const int qt   = (yy < 8) ? (15 - yy) : (yy - 8);
    const int b    = bh >> 4, h = bh & 15;
    const int g    = h >> 2;
    const int tid  = threadIdx.x;
    const int w    = tid >> 6;             // wave 0..7
    const int lane = tid & 63;
    const int lo16 = lane & 15;
    const int quad = lane >> 4;

    const unsigned short* Qb = Qh + (((size_t)b * H_   + h) * S_) * HD_;
    const unsigned short* Kb = Kh + (((size_t)b * KVH_ + g) * S_) * HD_;
    const unsigned short* Vb = Vt + (((size_t)b * KVH_ + g) * HD_) * S_;

    __shared__ __align__(16) unsigned short Ks[64][136];
    __shared__ __align__(16) unsigned short Vs[128][72];
    __shared__ __align__(16) unsigned short Ps[8][16][72];

    const int q0 = qt * 128;
    const int qw = q0 + w * 16;            // wave's 16 q-rows

    bf16x8 qf[4];
    #pragma unroll
    for (int kc = 0; kc < 4; ++kc)
        qf[kc] = *(const bf16x8*)(Qb + (size_t)(qw + lo16) * HD_ + kc * 32 + quad * 8);

    f32x4 o[8];
    #pragma unroll
    for (int n = 0; n < 8; ++n) o[n] = (f32x4){0.f, 0.f, 0.f, 0.f};
    float l_loc[4];
    #pragma unroll
    for (int r = 0; r < 4; ++r) l_loc[r] = 0.0f;

    // staging map (512 threads): K rows 32i+kr (kr 0..31), unit kcu 0..15;
    // V rows 64i+vr (vr 0..63), unit vcu 0..7. Plain unit addressing —
    // padded row stride provides the bank rotation.
    const int kr  = tid >> 4, kcu = tid & 15;
    const int vr  = tid >> 3, vcu = tid & 7;

    bf16x8 kreg[2], vreg[2];
    #pragma unroll
    for (int i = 0; i < 2; ++i) {
        kreg[i] = *(const bf16x8*)(Kb + (size_t)(32 * i + kr) * HD_ + kcu * 8);
        vreg[i] = *(const bf16x8*)(Vb + (size_t)(64 * i + vr) * S_ + vcu * 8);
    }

    const int ktend = 2 * qt + 1;          // block's last kv-tile
    for (int kt = 0; kt <= ktend; ++kt) {
        const int k0 = kt * 64;
        // barrier1: all waves consumed prev tile's Ks/Vs into regs
        asm volatile("s_barrier" ::: "memory");
        #pragma unroll
        for (int i = 0; i < 2; ++i) {
            *(bf16x8*)&Ks[32 * i + kr][kcu * 8] = kreg[i];
            *(bf16x8*)&Vs[64 * i + vr][vcu * 8] = vreg[i];
        }
        if (kt < ktend) {                  // prefetch next tile (uniform)
            const int k0n = k0 + 64;
            #pragma unroll
            for (int i = 0; i < 2; ++i) {
                kreg[i] = *(const bf16x8*)(Kb + (size_t)(k0n + 32 * i + kr) * HD_ + kcu * 8);
                vreg[i] = *(const bf16x8*)(Vb + (size_t)(64 * i + vr) * S_ + k0n + vcu * 8);
            }
        }
        // barrier2: ds_writes visible; vmcnt untouched (prefetch in flight)
        asm volatile("s_waitcnt lgkmcnt(0)" ::: "memory");
        asm volatile("s_barrier" ::: "memory");

        if (w >= 4 || kt < ktend) {
            f32x4 sc[4];
            #pragma unroll
            for (int cb = 0; cb < 4; ++cb) sc[cb] = (f32x4){0.f, 0.f, 0.f, 0.f};
            #pragma unroll
            for (int kc = 0; kc < 4; ++kc)
                #pragma unroll
                for (int cb = 0; cb < 4; ++cb) {
                    bf16x8 kf = *(const bf16x8*)&Ks[cb * 16 + lo16][kc * 32 + quad * 8];
                    sc[cb] = __builtin_amdgcn_mfma_f32_16x16x32_bf16(
                        qf[kc], kf, sc[cb], 0, 0, 0);
                }

            const bool masked = (w < 4) ? (kt == 2 * qt) : (kt == ktend);
            if (masked) {
                #pragma unroll
                for (int r = 0; r < 4; ++r) {
                    const int row = qw + quad * 4 + r;
                    float lacc = 0.0f;
                    #pragma unroll
                    for (int cb = 0; cb < 4; ++cb) {
                        float xv = sc[cb][r];
                        if ((k0 + cb * 16 + lo16) > row) xv = -1e30f;
                        float p = exp2f(xv);
                        lacc += p;
                        Ps[w][quad * 4 + r][cb * 16 + lo16] = f2bf_fast(p);
                    }
                    l_loc[r] += lacc;
                }
            } else {
                #pragma unroll
                for (int r = 0; r < 4; ++r) {
                    float lacc = 0.0f;
                    #pragma unroll
                    for (int cb = 0; cb < 4; ++cb) {
                        float p = exp2f(sc[cb][r]);
                        lacc += p;
                        Ps[w][quad * 4 + r][cb * 16 + lo16] = f2bf_fast(p);
                    }
                    l_loc[r] += lacc;
                }
            }

            #pragma unroll
            for (int kc = 0; kc < 2; ++kc) {
                bf16x8 pf = *(const bf16x8*)&Ps[w][lo16][kc * 32 + quad * 8];
                #pragma unroll
                for (int n = 0; n < 8; ++n) {
                    bf16x8 vf = *(const bf16x8*)&Vs[n * 16 + lo16][kc * 32 + quad * 8];
                    o[n] = __builtin_amdgcn_mfma_f32_16x16x32_bf16(
                        pf, vf, o[n], 0, 0, 0);
                }
            }
        }
    }

    #pragma unroll
    for (int r = 0; r < 4; ++r) {
        float l = l_loc[r];
        l += __shfl_xor(l, 1);
        l += __shfl_xor(l, 2);
        l += __shfl_xor(l, 4);
        l += __shfl_xor(l, 8);
        float invl = 1.0f / l;
        int srow = qw + quad * 4 + r;
        unsigned short* dst = attb + ((size_t)b * S_ + srow) * D_ + h * HD_;
        #pragma unroll
        for (int n = 0; n < 8; ++n)
            dst[n * 16 + lo16] = f2bf(o[n][r] * invl);
    }
}

// ---------------------------------------------------------------------------
// Output projection — 256x128 tile, BK=64, 8-wave (2Mx4N), 8-phase
// counted-vmcnt pipeline (unchanged from R4 — verified).
// ---------------------------------------------------------------------------
__global__ __launch_bounds__(512, 2) void out_mfma8(
    const unsigned short* __restrict__ Ah,
    const unsigned short* __restrict__ Wot,
    float* __restrict__ C)
{
    __shared__ __align__(16) unsigned short lds[49152];   // 96 KiB

    const int bid = blockIdx.x;
    const int swz = (bid & 7) * 32 + (bid >> 3);
    const int bm = swz >> 4, bn = swz & 15;
    const int m0 = bm * 256, n0 = bn * 128;

    const int tid  = threadIdx.x;
    const int w    = tid >> 6;             // wave 0..7
    const int lane = tid & 63;
    const int lo16 = lane & 15, quad = lane >> 4;
    const int wm   = w >> 2, wn = w & 3;   // 2M x 4N wave grid

    const unsigned short* Ag   = Ah  + (size_t)m0 * 2048;
    const unsigned short* AgH1 = Ag  + (size_t)128 * 2048;
    const unsigned short* Bt   = Wot + (size_t)n0 * 2048;

    const int rs   = lane >> 3;
    const int sce  = (((lane & 7) ^ rs) << 3);
    const int grow = w * 8 + rs;

    #define OSTAGE(gb, k0, lb) do {                                         \
        const unsigned short* _g = (gb) + (size_t)grow * 2048 + (k0) + sce; \
        gl_lds16(_g,                     (lb) + w * 512);                   \
        gl_lds16(_g + (size_t)64 * 2048, (lb) + (8 + w) * 512);             \
    } while (0)

    const int swb = (lo16 & 7) << 4;
    const int ac0 = (quad << 4) ^ swb;
    const int ac1 = (64 | (quad << 4)) ^ swb;
    char* ldsb = (char*)lds;
    const int abase = (wm * 128 + lo16) * 128;               // + mf*2048
    const int bbase = (wn * 32 + lo16) * 128 + 32768;        // + j*2048

    f32x4 acc[8][2];
    #pragma unroll
    for (int mf = 0; mf < 8; ++mf)
        #pragma unroll
        for (int j = 0; j < 2; ++j) acc[mf][j] = (f32x4){0.f, 0.f, 0.f, 0.f};

    bf16x8 a0[4][2], a1[4][2], bb[2][2];

    #define OMM(Aa, mo, j)                                                   \
        _Pragma("unroll") for (int mf = 0; mf < 4; ++mf) {                   \
            acc[(mo)+mf][j] = __builtin_amdgcn_mfma_f32_16x16x32_bf16(       \
                Aa[mf][0], bb[j][0], acc[(mo)+mf][j], 0, 0, 0);              \
            acc[(mo)+mf][j] = __builtin_amdgcn_mfma_f32_16x16x32_bf16(       \
                Aa[mf][1], bb[j][1], acc[(mo)+mf][j], 0, 0, 0);              \
        }

    OSTAGE(Bt,   0,  lds + 16384);
    OSTAGE(Ag,   0,  lds + 0);
    OSTAGE(AgH1, 0,  lds + 8192);
    OSTAGE(Bt,   64, lds + 24576 + 16384);
    OSTAGE(Ag,   64, lds + 24576);
    VMW4;
    PH_BAR();

    #define OPH(p, t)                                                            \
    {   _Pragma("unroll") for (int mf = 0; mf < 4; ++mf) {                       \
            a0[mf][0] = *(const bf16x8*)(ldsb + (p)*49152 + abase + mf*2048 + ac0); \
            a0[mf][1] = *(const bf16x8*)(ldsb + (p)*49152 + abase + mf*2048 + ac1); \
        }                                                                        \
        _Pragma("unroll") for (int j = 0; j < 2; ++j) {                          \
            bb[j][0] = *(const bf16x8*)(ldsb + (p)*49152 + bbase + j*2048 + ac0); \
            bb[j][1] = *(const bf16x8*)(ldsb + (p)*49152 + bbase + j*2048 + ac1); \
        }                                                                        \
        OSTAGE(AgH1, ((t)+1)*64, lds + ((p)^1)*24576 + 8192);                    \
        PH_BAR(); __builtin_amdgcn_s_setprio(1);                                 \
        OMM(a0, 0, 0);                                                           \
        __builtin_amdgcn_s_setprio(0); PH_BAR();                                 \
        OSTAGE(Bt, ((t)+2)*64, lds + (p)*24576 + 16384);                         \
        PH_BAR(); __builtin_amdgcn_s_setprio(1);                                 \
        OMM(a0, 0, 1);                                                           \
        __builtin_amdgcn_s_setprio(0); PH_BAR();                                 \
        _Pragma("unroll") for (int mf = 0; mf < 4; ++mf) {                       \
            a1[mf][0] = *(const bf16x8*)(ldsb + (p)*49152 + abase + (mf+4)*2048 + ac0); \
            a1[mf][1] = *(const bf16x8*)(ldsb + (p)*49152 + abase + (mf+4)*2048 + ac1); \
        }                                                                        \
        PH_BAR(); __builtin_amdgcn_s_setprio(1);                                 \
        OMM(a1, 4, 0);                                                           \
        __builtin_amdgcn_s_setprio(0); PH_BAR();                                 \
        OSTAGE(Ag, ((t)+2)*64, lds + (p)*24576);                                 \
        PH_BAR(); __builtin_amdgcn_s_setprio(1);                                 \
        OMM(a1, 4, 1);                                                           \
        __builtin_amdgcn_s_setprio(0);                                           \
        VMW4;                                                                    \
        PH_BAR();                                                                \
    }

    for (int it = 0; it < 16; ++it) {
        const int t = 2 * it;
        OPH(0, t);
        OPH(1, t + 1);
    }

    VMW0;

    #pragma unroll
    for (int mf = 0; mf < 8; ++mf)
        #pragma unroll
        for (int r = 0; r < 4; ++r) {
            size_t m = (size_t)(m0 + wm * 128 + mf * 16 + quad * 4 + r);
            #pragma unroll
            for (int j = 0; j < 2; ++j)
                C[m * 2048 + n0 + wn * 32 + j * 16 + lo16] = acc[mf][j][r];
        }
    #undef OPH
    #undef OMM
    #undef OSTAGE
}

// ---------------------------------------------------------------------------
// Workspace layout (bf16 shorts), total 60 MB:
//   xh/attb : 0    .. 16 MB   (xh dead after qkv -> attb aliases it)
//   Wqt     : 16   .. 24 MB
//   Wkt     : 24   .. 26 MB
//   Wvt     : 26   .. 28 MB
//   Wot     : 28   .. 36 MB
//   Qh      : 36   .. 52 MB
//   Kh      : 52   .. 56 MB
//   Vt      : 56   .. 60 MB
// ---------------------------------------------------------------------------
extern "C" void kernel_launch(void* const* d_in, const int* in_sizes, int n_in,
                              void* d_out, int out_size, void* d_ws, size_t ws_size,
                              hipStream_t stream)
{
    const float* x  = (const float*)d_in[0];
    const float* Wq = (const float*)d_in[1];
    const float* Wk = (const float*)d_in[2];
    const float* Wv = (const float*)d_in[3];
    const float* Wo = (const float*)d_in[4];
    float* out = (float*)d_out;

    unsigned short* xh  = (unsigned short*)d_ws;
    unsigned short* Wqt = xh  + (size_t)4096 * 2048;
    unsigned short* Wkt = Wqt + (size_t)2048 * 2048;
    unsigned short* Wvt = Wkt + (size_t)512 * 2048;
    unsigned short* Wot = Wvt + (size_t)512 * 2048;
    unsigned short* Qh  = Wot + (size_t)2048 * 2048;
    unsigned short* Kh  = Qh  + (size_t)B_ * H_   * S_ * HD_;
    unsigned short* Vt  = Kh  + (size_t)B_ * KVH_ * S_ * HD_;
    unsigned short* attb= xh;   // reuse: xh dead after qkv_mfma8

    cast_bf16<<<(4096 * 2048 / 4 + 255) / 256, 256, 0, stream>>>(x, xh, 4096 * 2048 / 4);
    cast_transpose_all<<<dim3(64, 160), 256, 0, stream>>>(Wq, Wk, Wv, Wo, Wqt, Wkt, Wvt, Wot);

    qkv_mfma8<<<192, 512, 0, stream>>>(xh, Wqt, Wkt, Wvt, Qh, Kh, Vt);

    flash_attn_mfma<<<dim3(32, 16), 512, 0, stream>>>(Qh, Kh, Vt, attb);

    out_mfma8<<<256, 512, 0, stream>>>(attb, Wot, out);
}

// Round 14
// 272.631 us; speedup vs baseline: 1.0948x; 1.0035x over previous
//
#include <hip/hip_runtime.h>
#include <math.h>

#define B_   2
#define S_   2048
#define D_   2048
#define H_   16
#define KVH_ 4
#define HD_  128
#define REP_ 4

typedef __attribute__((ext_vector_type(8))) short bf16x8;
typedef __attribute__((ext_vector_type(4))) short bf16x4;
typedef __attribute__((ext_vector_type(4))) float f32x4;

// 1/sqrt(128) * log2(e): folded into Q so flash scores are base-2 pre-scaled
#define QSCALE_LOG2E 0.1275266977097153f

__device__ __forceinline__ unsigned short f2bf(float x) {
    union { float f; unsigned u; } v; v.f = x;
    unsigned r = v.u + 0x7FFF + ((v.u >> 16) & 1);   // RNE
    return (unsigned short)(r >> 16);
}

// cheap round-half-up bf16 (used only for P; bias cancels in p/sum(p))
__device__ __forceinline__ unsigned short f2bf_fast(float x) {
    union { float f; unsigned u; } v; v.f = x;
    return (unsigned short)((v.u + 0x8000) >> 16);
}

// async global->LDS, 16B per lane; LDS dest is wave-uniform base + lane*16
__device__ __forceinline__ void gl_lds16(const unsigned short* g, unsigned short* l) {
    __builtin_amdgcn_global_load_lds(
        (const __attribute__((address_space(1))) unsigned int*)g,
        (__attribute__((address_space(3))) unsigned int*)l,
        16, 0, 0);
}

#define PH_BAR() do { asm volatile("" ::: "memory"); \
                      __builtin_amdgcn_s_barrier();  \
                      asm volatile("" ::: "memory"); } while (0)
#define VMW6 asm volatile("s_waitcnt vmcnt(6)" ::: "memory")
#define VMW4 asm volatile("s_waitcnt vmcnt(4)" ::: "memory")
#define VMW0 asm volatile("s_waitcnt vmcnt(0)" ::: "memory")

// ---------------------------------------------------------------------------
// cast fp32 -> bf16 (elementwise)
// ---------------------------------------------------------------------------
__global__ void cast_bf16(const float* __restrict__ src,
                          unsigned short* __restrict__ dst, int n4)
{
    int i = blockIdx.x * 256 + threadIdx.x;
    if (i >= n4) return;
    float4 v = *(const float4*)&src[(size_t)i * 4];
    bf16x4 o;
    o[0] = (short)f2bf(v.x); o[1] = (short)f2bf(v.y);
    o[2] = (short)f2bf(v.z); o[3] = (short)f2bf(v.w);
    *(bf16x4*)&dst[(size_t)i * 4] = o;
}

// ---------------------------------------------------------------------------
// fused cast+transpose of all 4 weights: src [2048][C] fp32 -> dst [C][2048].
// blockIdx.y: [0,64) Wq | [64,80) Wk | [80,96) Wv | [96,160) Wo
// ---------------------------------------------------------------------------
__global__ __launch_bounds__(256) void cast_transpose_all(
    const float* __restrict__ Wq, const float* __restrict__ Wk,
    const float* __restrict__ Wv, const float* __restrict__ Wo,
    unsigned short* __restrict__ Wqt, unsigned short* __restrict__ Wkt,
    unsigned short* __restrict__ Wvt, unsigned short* __restrict__ Wot)
{
    __shared__ float T[32][33];
    const int y = blockIdx.y;
    const float* src; unsigned short* dst; int C, bj;
    if (y < 64)      { src = Wq; dst = Wqt; C = 2048; bj = y; }
    else if (y < 80) { src = Wk; dst = Wkt; C = 512;  bj = y - 64; }
    else if (y < 96) { src = Wv; dst = Wvt; C = 512;  bj = y - 80; }
    else             { src = Wo; dst = Wot; C = 2048; bj = y - 96; }

    const int bi = blockIdx.x;
    const int t  = threadIdx.x;
    const int r  = t >> 3, cq = (t & 7) * 4;

    float4 v = *(const float4*)&src[(size_t)(bi * 32 + r) * C + bj * 32 + cq];
    T[r][cq + 0] = v.x; T[r][cq + 1] = v.y;
    T[r][cq + 2] = v.z; T[r][cq + 3] = v.w;
    __syncthreads();

    bf16x4 o;
    o[0] = (short)f2bf(T[cq + 0][r]);
    o[1] = (short)f2bf(T[cq + 1][r]);
    o[2] = (short)f2bf(T[cq + 2][r]);
    o[3] = (short)f2bf(T[cq + 3][r]);
    *(bf16x4*)&dst[(size_t)(bj * 32 + r) * 2048 + bi * 32 + cq] = o;
}

// ---------------------------------------------------------------------------
// Fused QKV projection v2 — 128x384 tile, BK=64, 8-wave (2Mx4N), 3-phase
// counted-vmcnt pipeline. Grid 32x8 = 256 blocks = 1/CU (the 256x256 tile
// gave only 192 blocks -> 25% of CUs idle; out_mfma8 at 1/CU runs 650 TF).
//   LDS 128KiB: buf p at byte p*65536: A[128][64] @ +0, B^T[384][64] @ +16384.
//   Wave (wm,wn): 64 rows x 6 frags, cmap {g*8+wn, g*8+wn+4 | g=0..2} ->
//   RoPE pairs (d,d+64) in-register for every head; tile spans 3 heads,
//   epilogue branches per head-group (block-uniform -> barrier-safe).
//   Stages: P1 A(t+1)->p^1 (B(t) fully read in P1 first), P2 B0(t+2)->p,
//   P3 B1,B2(t+2)->p; vmcnt(6) at tile end leaves the 3 newest halves.
//   K order unchanged -> bit-identical outputs.
// ---------------------------------------------------------------------------
__global__ __launch_bounds__(512, 2) void qkv_mfma12(
    const unsigned short* __restrict__ Ah,
    const unsigned short* __restrict__ Wqt,
    const unsigned short* __restrict__ Wkt,
    const unsigned short* __restrict__ Wvt,
    unsigned short* __restrict__ Qh, unsigned short* __restrict__ Kh,
    unsigned short* __restrict__ Vt)
{
    __shared__ __align__(16) unsigned short lds[65536];   // 128 KiB

    // XCD swizzle: 256 wgs = 8 XCD x 32; each XCD owns one bn column
    // (B panel 1.5MB L2-resident) across all 32 bm.
    const int bid = blockIdx.x;
    const int swz = (bid & 7) * 32 + (bid >> 3);
    const int bn = swz >> 5, bm = swz & 31;
    const int m0 = bm * 128, n0 = bn * 384;

    const int tid  = threadIdx.x;
    const int w    = tid >> 6;             // wave 0..7
    const int lane = tid & 63;
    const int lo16 = lane & 15, quad = lane >> 4;
    const int wm   = w >> 2, wn = w & 3;   // 2M x 4N wave grid

    // B columns n0..n0+383 may span Wqt/Wkt/Wvt; all three are contiguous
    // in workspace (Wqt|Wkt|Wvt back-to-back), so a single base works:
    const unsigned short* Wall = Wqt;      // rows 0..3071 across the 3 arrays
    const unsigned short* Bt   = Wall + (size_t)n0 * 2048;
    const unsigned short* B1g  = Bt + (size_t)128 * 2048;
    const unsigned short* B2g  = Bt + (size_t)256 * 2048;
    const unsigned short* Ag   = Ah + (size_t)m0 * 2048;

    const int rs   = lane >> 3;                      // 0..7
    const int sce  = (((lane & 7) ^ rs) << 3);       // swizzled col (shorts)
    const int grow = w * 8 + rs;                     // 0..63

    #define STAGE(gb, k0, lb) do {                                          \
        const unsigned short* _g = (gb) + (size_t)grow * 2048 + (k0) + sce; \
        gl_lds16(_g,                     (lb) + w * 512);                   \
        gl_lds16(_g + (size_t)64 * 2048, (lb) + (8 + w) * 512);             \
    } while (0)

    const int swb = (lo16 & 7) << 4;
    const int ac0 = (quad << 4) ^ swb;               // ks=0 (cols 0..31)
    const int ac1 = (64 | (quad << 4)) ^ swb;        // ks=1 (cols 32..63)
    char* ldsb = (char*)lds;
    const int abase = (wm * 64 + lo16) * 128;                // + mf*2048
    // b frag f: byte 16384 + (f*16 + lo16)*128 + ac

    f32x4 acc[4][6];
    #pragma unroll
    for (int mf = 0; mf < 4; ++mf)
        #pragma unroll
        for (int j = 0; j < 6; ++j) acc[mf][j] = (f32x4){0.f, 0.f, 0.f, 0.f};

    bf16x8 af[4][2], bf[3][2][2];

    // MFMA for head-group g: acc[mf][2g+jj] += af[mf][ks] x bf[g][jj][ks]
    #define MMG(g)                                                           \
        _Pragma("unroll") for (int mf = 0; mf < 4; ++mf)                     \
        _Pragma("unroll") for (int jj = 0; jj < 2; ++jj) {                   \
            acc[mf][2*(g)+jj] = __builtin_amdgcn_mfma_f32_16x16x32_bf16(     \
                af[mf][0], bf[g][jj][0], acc[mf][2*(g)+jj], 0, 0, 0);        \
            acc[mf][2*(g)+jj] = __builtin_amdgcn_mfma_f32_16x16x32_bf16(     \
                af[mf][1], bf[g][jj][1], acc[mf][2*(g)+jj], 0, 0, 0);        \
        }

    // Prologue: B(0) trio + A(0) + B(1) trio = 7 halves = 14 loads;
    // vmcnt(6) -> the 8 oldest (tile0's 4 halves + B1(1)) complete.
    STAGE(Bt,  0, lds + 8192);
    STAGE(B1g, 0, lds + 16384);
    STAGE(B2g, 0, lds + 24576);
    STAGE(Ag,  0, lds + 0);
    STAGE(Bt,  64, lds + 32768 + 8192);
    STAGE(B1g, 64, lds + 32768 + 16384);
    STAGE(B2g, 64, lds + 32768 + 24576);
    VMW6;
    PH_BAR();

    // Tile t in buf p. P1 reads ALL a+b frags (so later B stages into p are
    // safe), stages A(t+1)->p^1; P2 stages B0(t+2)->p; P3 stages B1,B2(t+2).
    // End-of-tile vmcnt(6): 3 newest halves (B trio t+2) in flight;
    // A(t+1) 4th-newest -> landed; B(t+1) trio 5th-7th -> landed.
    #define QPH(p, t)                                                            \
    {   _Pragma("unroll") for (int mf = 0; mf < 4; ++mf) {                       \
            af[mf][0] = *(const bf16x8*)(ldsb + (p)*65536 + abase + mf*2048 + ac0); \
            af[mf][1] = *(const bf16x8*)(ldsb + (p)*65536 + abase + mf*2048 + ac1); \
        }                                                                        \
        _Pragma("unroll") for (int g = 0; g < 3; ++g)                            \
        _Pragma("unroll") for (int jj = 0; jj < 2; ++jj) {                       \
            const int f = g * 8 + wn + jj * 4;                                   \
            bf[g][jj][0] = *(const bf16x8*)(ldsb + (p)*65536 + 16384             \
                                            + (f*16 + lo16)*128 + ac0);          \
            bf[g][jj][1] = *(const bf16x8*)(ldsb + (p)*65536 + 16384             \
                                            + (f*16 + lo16)*128 + ac1);          \
        }                                                                        \
        STAGE(Ag, ((t)+1)*64, lds + ((p)^1)*32768);                              \
        PH_BAR(); __builtin_amdgcn_s_setprio(1);                                 \
        MMG(0);                                                                  \
        __builtin_amdgcn_s_setprio(0); PH_BAR();                                 \
        STAGE(Bt, ((t)+2)*64, lds + (p)*32768 + 8192);                           \
        PH_BAR(); __builtin_amdgcn_s_setprio(1);                                 \
        MMG(1);                                                                  \
        __builtin_amdgcn_s_setprio(0); PH_BAR();                                 \
        STAGE(B1g, ((t)+2)*64, lds + (p)*32768 + 16384);                         \
        STAGE(B2g, ((t)+2)*64, lds + (p)*32768 + 24576);                         \
        PH_BAR(); __builtin_amdgcn_s_setprio(1);                                 \
        MMG(2);                                                                  \
        __builtin_amdgcn_s_setprio(0);                                           \
        VMW6;                                                                    \
        PH_BAR();                                                                \
    }

    for (int it = 0; it < 16; ++it) {
        const int t = 2 * it;
        QPH(0, t);
        QPH(1, t + 1);
    }
    // (Tail stages for t+1/t+2 >= 32 read allocated workspace past the
    //  matrices — in-bounds, never consumed.)

    // Drain ALL LDS-DMA before epilogue (retire hazard + Ts reuses lds).
    VMW0;
    PH_BAR();

    const int bb = m0 >> 11;        // 128-row tile never crosses batch
    const int s0loc = m0 & 2047;
    const int d = wn * 16 + lo16;                    // 0..63, same for all g
    const float inv = exp2f(-(float)d * 0.20761871093344086f);
    unsigned short* Ts = lds;                        // [128][136]

    #pragma unroll
    for (int g = 0; g < 3; ++g) {
        const int cg = n0 + g * 128;                 // block-uniform
        if (cg < 2560) {
            // ---- Q or K head: RoPE in registers ----
            const bool isQ = (cg < 2048);
            const float post = isQ ? QSCALE_LOG2E : 1.0f;
            unsigned short* dstb = isQ
                ? Qh + (((size_t)bb * H_   + (cg >> 7))          * S_) * HD_
                : Kh + (((size_t)bb * KVH_ + ((cg - 2048) >> 7)) * S_) * HD_;
            #pragma unroll
            for (int mf = 0; mf < 4; ++mf) {
                #pragma unroll
                for (int r = 0; r < 4; ++r) {
                    int s = s0loc + wm * 64 + mf * 16 + quad * 4 + r;
                    float sn, c;
                    sincosf((float)s * inv, &sn, &c);
                    float lo = acc[mf][2 * g + 0][r];
                    float hi = acc[mf][2 * g + 1][r];
                    unsigned short* drow = dstb + (size_t)s * HD_;
                    drow[d]      = f2bf((lo * c - hi * sn) * post);
                    drow[d + 64] = f2bf((hi * c + lo * sn) * post);
                }
            }
        } else {
            // ---- V head: 128x128 transpose via LDS, b128 stores ----
            const int g0 = (cg - 2560) >> 7;
            PH_BAR();                                // prior Ts users done
            #pragma unroll
            for (int mf = 0; mf < 4; ++mf) {
                int ml = wm * 64 + mf * 16 + quad * 4;
                bf16x4 v0, v1;
                #pragma unroll
                for (int r = 0; r < 4; ++r) {
                    v0[r] = (short)f2bf(acc[mf][2 * g + 0][r]);
                    v1[r] = (short)f2bf(acc[mf][2 * g + 1][r]);
                }
                *(bf16x4*)&Ts[(size_t)d        * 136 + ml] = v0;
                *(bf16x4*)&Ts[(size_t)(d + 64) * 136 + ml] = v1;
            }
            PH_BAR();
            unsigned short* dstb = Vt + (((size_t)bb * KVH_ + g0) * HD_) * S_ + s0loc;
            #pragma unroll
            for (int itb = 0; itb < 4; ++itb) {
                int dd = itb * 32 + (tid >> 4);
                int ch = (tid & 15) * 8;
                *(bf16x8*)(dstb + (size_t)dd * S_ + ch) =
                    *(const bf16x8*)&Ts[(size_t)dd * 136 + ch];
            }
        }
    }
    #undef QPH
    #undef MMG
    #undef STAGE
}

// ---------------------------------------------------------------------------
// Flash attention v8 (best-measured, 73.5-75 us): 8 waves x 16 q-rows,
// plain padded LDS, plain-barrier + lgkm-only-barrier per tile, register
// prefetch. Unchanged from R13.
// ---------------------------------------------------------------------------
__global__ __launch_bounds__(512, 4) void flash_attn_mfma(
    const unsigned short* __restrict__ Qh,
    const unsigned short* __restrict__ Kh,
    const unsigned short* __restrict__ Vt,
    unsigned short* __restrict__ attb)
{
    const int bh   = blockIdx.x;           // 0..31
    const int yy   = blockIdx.y;           // 0..15
    const int qt   = (yy < 8) ? (15 - yy) : (yy - 8);
    const int b    = bh >> 4, h = bh & 15;
    const int g    = h >> 2;
    const int tid  = threadIdx.x;
    const int w    = tid >> 6;             // wave 0..7
    const int lane = tid & 63;
    const int lo16 = lane & 15;
    const int quad = lane >> 4;

    const unsigned short* Qb = Qh + (((size_t)b * H_   + h) * S_) * HD_;
    const unsigned short* Kb = Kh + (((size_t)b * KVH_ + g) * S_) * HD_;
    const unsigned short* Vb = Vt + (((size_t)b * KVH_ + g) * HD_) * S_;

    __shared__ __align__(16) unsigned short Ks[64][136];
    __shared__ __align__(16) unsigned short Vs[128][72];
    __shared__ __align__(16) unsigned short Ps[8][16][72];

    const int q0 = qt * 128;
    const int qw = q0 + w * 16;            // wave's 16 q-rows

    bf16x8 qf[4];
    #pragma unroll
    for (int kc = 0; kc < 4; ++kc)
        qf[kc] = *(const bf16x8*)(Qb + (size_t)(qw + lo16) * HD_ + kc * 32 + quad * 8);

    f32x4 o[8];
    #pragma unroll
    for (int n = 0; n < 8; ++n) o[n] = (f32x4){0.f, 0.f, 0.f, 0.f};
    float l_loc[4];
    #pragma unroll
    for (int r = 0; r < 4; ++r) l_loc[r] = 0.0f;

    const int kr  = tid >> 4, kcu = tid & 15;
    const int vr  = tid >> 3, vcu = tid & 7;

    bf16x8 kreg[2], vreg[2];
    #pragma unroll
    for (int i = 0; i < 2; ++i) {
        kreg[i] = *(const bf16x8*)(Kb + (size_t)(32 * i + kr) * HD_ + kcu * 8);
        vreg[i] = *(const bf16x8*)(Vb + (size_t)(64 * i + vr) * S_ + vcu * 8);
    }

    const int ktend = 2 * qt + 1;          // block's last kv-tile
    for (int kt = 0; kt <= ktend; ++kt) {
        const int k0 = kt * 64;
        // barrier1: all waves consumed prev tile's Ks/Vs into regs
        asm volatile("s_barrier" ::: "memory");
        #pragma unroll
        for (int i = 0; i < 2; ++i) {
            *(bf16x8*)&Ks[32 * i + kr][kcu * 8] = kreg[i];
            *(bf16x8*)&Vs[64 * i + vr][vcu * 8] = vreg[i];
        }
        if (kt < ktend) {                  // prefetch next tile (uniform)
            const int k0n = k0 + 64;
            #pragma unroll
            for (int i = 0; i < 2; ++i) {
                kreg[i] = *(const bf16x8*)(Kb + (size_t)(k0n + 32 * i + kr) * HD_ + kcu * 8);
                vreg[i] = *(const bf16x8*)(Vb + (size_t)(64 * i + vr) * S_ + k0n + vcu * 8);
            }
        }
        // barrier2: ds_writes visible; vmcnt untouched (prefetch in flight)
        asm volatile("s_waitcnt lgkmcnt(0)" ::: "memory");
        asm volatile("s_barrier" ::: "memory");

        if (w >= 4 || kt < ktend) {
            f32x4 sc[4];
            #pragma unroll
            for (int cb = 0; cb < 4; ++cb) sc[cb] = (f32x4){0.f, 0.f, 0.f, 0.f};
            #pragma unroll
            for (int kc = 0; kc < 4; ++kc)
                #pragma unroll
                for (int cb = 0; cb < 4; ++cb) {
                    bf16x8 kf = *(const bf16x8*)&Ks[cb * 16 + lo16][kc * 32 + quad * 8];
                    sc[cb] = __builtin_amdgcn_mfma_f32_16x16x32_bf16(
                        qf[kc], kf, sc[cb], 0, 0, 0);
                }

            const bool masked = (w < 4) ? (kt == 2 * qt) : (kt == ktend);
            if (masked) {
                #pragma unroll
                for (int r = 0; r < 4; ++r) {
                    const int row = qw + quad * 4 + r;
                    float lacc = 0.0f;
                    #pragma unroll
                    for (int cb = 0; cb < 4; ++cb) {
                        float xv = sc[cb][r];
                        if ((k0 + cb * 16 + lo16) > row) xv = -1e30f;
                        float p = exp2f(xv);
                        lacc += p;
                        Ps[w][quad * 4 + r][cb * 16 + lo16] = f2bf_fast(p);
                    }
                    l_loc[r] += lacc;
                }
            } else {
                #pragma unroll
                for (int r = 0; r < 4; ++r) {
                    float lacc = 0.0f;
                    #pragma unroll
                    for (int cb = 0; cb < 4; ++cb) {
                        float p = exp2f(sc[cb][r]);
                        lacc += p;
                        Ps[w][quad * 4 + r][cb * 16 + lo16] = f2bf_fast(p);
                    }
                    l_loc[r] += lacc;
                }
            }

            #pragma unroll
            for (int kc = 0; kc < 2; ++kc) {
                bf16x8 pf = *(const bf16x8*)&Ps[w][lo16][kc * 32 + quad * 8];
                #pragma unroll
                for (int n = 0; n < 8; ++n) {
                    bf16x8 vf = *(const bf16x8*)&Vs[n * 16 + lo16][kc * 32 + quad * 8];
                    o[n] = __builtin_amdgcn_mfma_f32_16x16x32_bf16(
                        pf, vf, o[n], 0, 0, 0);
                }
            }
        }
    }

    #pragma unroll
    for (int r = 0; r < 4; ++r) {
        float l = l_loc[r];
        l += __shfl_xor(l, 1);
        l += __shfl_xor(l, 2);
        l += __shfl_xor(l, 4);
        l += __shfl_xor(l, 8);
        float invl = 1.0f / l;
        int srow = qw + quad * 4 + r;
        unsigned short* dst = attb + ((size_t)b * S_ + srow) * D_ + h * HD_;
        #pragma unroll
        for (int n = 0; n < 8; ++n)
            dst[n * 16 + lo16] = f2bf(o[n][r] * invl);
    }
}

// ---------------------------------------------------------------------------
// Output projection — 256x128 tile, BK=64, 8-wave (2Mx4N), 8-phase
// counted-vmcnt pipeline (unchanged from R4 — verified).
// ---------------------------------------------------------------------------
__global__ __launch_bounds__(512, 2) void out_mfma8(
    const unsigned short* __restrict__ Ah,
    const unsigned short* __restrict__ Wot,
    float* __restrict__ C)
{
    __shared__ __align__(16) unsigned short lds[49152];   // 96 KiB

    const int bid = blockIdx.x;
    const int swz = (bid & 7) * 32 + (bid >> 3);
    const int bm = swz >> 4, bn = swz & 15;
    const int m0 = bm * 256, n0 = bn * 128;

    const int tid  = threadIdx.x;
    const int w    = tid >> 6;             // wave 0..7
    const int lane = tid & 63;
    const int lo16 = lane & 15, quad = lane >> 4;
    const int wm   = w >> 2, wn = w & 3;   // 2M x 4N wave grid

    const unsigned short* Ag   = Ah  + (size_t)m0 * 2048;
    const unsigned short* AgH1 = Ag  + (size_t)128 * 2048;
    const unsigned short* Bt   = Wot + (size_t)n0 * 2048;

    const int rs   = lane >> 3;
    const int sce  = (((lane & 7) ^ rs) << 3);
    const int grow = w * 8 + rs;

    #define OSTAGE(gb, k0, lb) do {                                         \
        const unsigned short* _g = (gb) + (size_t)grow * 2048 + (k0) + sce; \
        gl_lds16(_g,                     (lb) + w * 512);                   \
        gl_lds16(_g + (size_t)64 * 2048, (lb) + (8 + w) * 512);             \
    } while (0)

    const int swb = (lo16 & 7) << 4;
    const int ac0 = (quad << 4) ^ swb;
    const int ac1 = (64 | (quad << 4)) ^ swb;
    char* ldsb = (char*)lds;
    const int abase = (wm * 128 + lo16) * 128;               // + mf*2048
    const int bbase = (wn * 32 + lo16) * 128 + 32768;        // + j*2048

    f32x4 acc[8][2];
    #pragma unroll
    for (int mf = 0; mf < 8; ++mf)
        #pragma unroll
        for (int j = 0; j < 2; ++j) acc[mf][j] = (f32x4){0.f, 0.f, 0.f, 0.f};

    bf16x8 a0[4][2], a1[4][2], bb[2][2];

    #define OMM(Aa, mo, j)                                                   \
        _Pragma("unroll") for (int mf = 0; mf < 4; ++mf) {                   \
            acc[(mo)+mf][j] = __builtin_amdgcn_mfma_f32_16x16x32_bf16(       \
                Aa[mf][0], bb[j][0], acc[(mo)+mf][j], 0, 0, 0);              \
            acc[(mo)+mf][j] = __builtin_amdgcn_mfma_f32_16x16x32_bf16(       \
                Aa[mf][1], bb[j][1], acc[(mo)+mf][j], 0, 0, 0);              \
        }

    OSTAGE(Bt,   0,  lds + 16384);
    OSTAGE(Ag,   0,  lds + 0);
    OSTAGE(AgH1, 0,  lds + 8192);
    OSTAGE(Bt,   64, lds + 24576 + 16384);
    OSTAGE(Ag,   64, lds + 24576);
    VMW4;
    PH_BAR();

    #define OPH(p, t)                                                            \
    {   _Pragma("unroll") for (int mf = 0; mf < 4; ++mf) {                       \
            a0[mf][0] = *(const bf16x8*)(ldsb + (p)*49152 + abase + mf*2048 + ac0); \
            a0[mf][1] = *(const bf16x8*)(ldsb + (p)*49152 + abase + mf*2048 + ac1); \
        }                                                                        \
        _Pragma("unroll") for (int j = 0; j < 2; ++j) {                          \
            bb[j][0] = *(const bf16x8*)(ldsb + (p)*49152 + bbase + j*2048 + ac0); \
            bb[j][1] = *(const bf16x8*)(ldsb + (p)*49152 + bbase + j*2048 + ac1); \
        }                                                                        \
        OSTAGE(AgH1, ((t)+1)*64, lds + ((p)^1)*24576 + 8192);                    \
        PH_BAR(); __builtin_amdgcn_s_setprio(1);                                 \
        OMM(a0, 0, 0);                                                           \
        __builtin_amdgcn_s_setprio(0); PH_BAR();                                 \
        OSTAGE(Bt, ((t)+2)*64, lds + (p)*24576 + 16384);                         \
        PH_BAR(); __builtin_amdgcn_s_setprio(1);                                 \
        OMM(a0, 0, 1);                                                           \
        __builtin_amdgcn_s_setprio(0); PH_BAR();                                 \
        _Pragma("unroll") for (int mf = 0; mf < 4; ++mf) {                       \
            a1[mf][0] = *(const bf16x8*)(ldsb + (p)*49152 + abase + (mf+4)*2048 + ac0); \
            a1[mf][1] = *(const bf16x8*)(ldsb + (p)*49152 + abase + (mf+4)*2048 + ac1); \
        }                                                                        \
        PH_BAR(); __builtin_amdgcn_s_setprio(1);                                 \
        OMM(a1, 4, 0);                                                           \
        __builtin_amdgcn_s_setprio(0); PH_BAR();                                 \
        OSTAGE(Ag, ((t)+2)*64, lds + (p)*24576);                                 \
        PH_BAR(); __builtin_amdgcn_s_setprio(1);                                 \
        OMM(a1, 4, 1);                                                           \
        __builtin_amdgcn_s_setprio(0);                                           \
        VMW4;                                                                    \
        PH_BAR();                                                                \
    }

    for (int it = 0; it < 16; ++it) {
        const int t = 2 * it;
        OPH(0, t);
        OPH(1, t + 1);
    }

    VMW0;

    #pragma unroll
    for (int mf = 0; mf < 8; ++mf)
        #pragma unroll
        for (int r = 0; r < 4; ++r) {
            size_t m = (size_t)(m0 + wm * 128 + mf * 16 + quad * 4 + r);
            #pragma unroll
            for (int j = 0; j < 2; ++j)
                C[m * 2048 + n0 + wn * 32 + j * 16 + lo16] = acc[mf][j][r];
        }
    #undef OPH
    #undef OMM
    #undef OSTAGE
}

// ---------------------------------------------------------------------------
// Workspace layout (bf16 shorts), total 60 MB:
//   xh/attb : 0    .. 16 MB   (xh dead after qkv -> attb aliases it)
//   Wqt     : 16   .. 24 MB   (Wqt|Wkt|Wvt contiguous: one 3072-row B array)
//   Wkt     : 24   .. 26 MB
//   Wvt     : 26   .. 28 MB
//   Wot     : 28   .. 36 MB
//   Qh      : 36   .. 52 MB
//   Kh      : 52   .. 56 MB
//   Vt      : 56   .. 60 MB
// ---------------------------------------------------------------------------
extern "C" void kernel_launch(void* const* d_in, const int* in_sizes, int n_in,
                              void* d_out, int out_size, void* d_ws, size_t ws_size,
                              hipStream_t stream)
{
    const float* x  = (const float*)d_in[0];
    const float* Wq = (const float*)d_in[1];
    const float* Wk = (const float*)d_in[2];
    const float* Wv = (const float*)d_in[3];
    const float* Wo = (const float*)d_in[4];
    float* out = (float*)d_out;

    unsigned short* xh  = (unsigned short*)d_ws;
    unsigned short* Wqt = xh  + (size_t)4096 * 2048;
    unsigned short* Wkt = Wqt + (size_t)2048 * 2048;
    unsigned short* Wvt = Wkt + (size_t)512 * 2048;
    unsigned short* Wot = Wvt + (size_t)512 * 2048;
    unsigned short* Qh  = Wot + (size_t)2048 * 2048;
    unsigned short* Kh  = Qh  + (size_t)B_ * H_   * S_ * HD_;
    unsigned short* Vt  = Kh  + (size_t)B_ * KVH_ * S_ * HD_;
    unsigned short* attb= xh;   // reuse: xh dead after qkv

    cast_bf16<<<(4096 * 2048 / 4 + 255) / 256, 256, 0, stream>>>(x, xh, 4096 * 2048 / 4);
    cast_transpose_all<<<dim3(64, 160), 256, 0, stream>>>(Wq, Wk, Wv, Wo, Wqt, Wkt, Wvt, Wot);

    qkv_mfma12<<<256, 512, 0, stream>>>(xh, Wqt, Wkt, Wvt, Qh, Kh, Vt);

    flash_attn_mfma<<<dim3(32, 16), 512, 0, stream>>>(Qh, Kh, Vt, attb);

    out_mfma8<<<256, 512, 0, stream>>>(attb, Wot, out);
}